// Round 4
// baseline (18.360 us; speedup 1.0000x reference)
//
#include <hip/hip_runtime.h>

// Fused quantum-transformer block, v4.
//  - prep kernel packs Wc/W1/W2 into fp16 pairs in d_ws (dot2-ready)
//  - main kernel: 512 blocks x 256 thr, 2 tokens/wave -> 2 blocks/CU
//    (2 waves/SIMD), zero LDS, zero barriers, readlane + v_dot2_f32_f16.
//
// Closed-form circuit (verified round 1): OPS = ry(0,t0) rx(3,t1) rz(5,t2)
// cx(1,4) ry(6,t3) rx(2,t4) cx(0,7) rz(4,t5) on RX(a_w)-encoded product state.
//   z0 = cos(t0) cos(a0)          z4 = cos(a1) cos(a4)
//   z1 = cos(a1)                  z5 = cos(a5)
//   z2 = cos(a2 + t4)             z6 = cos(t3) cos(a6)
//   z3 = cos(a3 + t1)             z7 = cos(t0) cos(a0) cos(a7)
//
// ws layout (int32 half2 words):
//   pWc [32][64]  @ 0     : (Wc[q][e],  Wc[q+32][e])
//   pW1 [4][256]  @ 2048  : (W1[k][j],  W1[k+4][j])
//   pW2a[64][64]  @ 3072  : (W2[kk][e], W2[kk+64][e])
//   pW2b[64][64]  @ 7168  : (W2[kk+128][e], W2[kk+192][e])
//   total 11264 ints = 45056 B

typedef _Float16 h2f __attribute__((ext_vector_type(2)));

__device__ __forceinline__ int pk(float a, float b) {
    return __builtin_bit_cast(int, __builtin_amdgcn_cvt_pkrtz(a, b));
}
__device__ __forceinline__ float fdot2i(int a, int b, float c) {
    return __builtin_amdgcn_fdot2(__builtin_bit_cast(h2f, a),
                                  __builtin_bit_cast(h2f, b), c, false);
}
__device__ __forceinline__ float rl_f(float v, int l) {
    return __int_as_float(__builtin_amdgcn_readlane(__float_as_int(v), l));
}
__device__ __forceinline__ int rl_i(int v, int l) {
    return __builtin_amdgcn_readlane(v, l);
}
__device__ __forceinline__ void wave_sum2(float& a, float& b) {
#pragma unroll
    for (int m = 32; m > 0; m >>= 1) {
        a += __shfl_xor(a, m, 64);
        b += __shfl_xor(b, m, 64);
    }
}

__global__ __launch_bounds__(256)
void qtb_pack(const float* __restrict__ Wc, const float* __restrict__ W1,
              const float* __restrict__ W2, int* __restrict__ pw)
{
    int g = blockIdx.x * 256 + threadIdx.x;   // 44 blocks -> 11264 threads
    if (g < 2048) {
        int q = g >> 6, e = g & 63;
        pw[g] = pk(Wc[q * 64 + e], Wc[(q + 32) * 64 + e]);
    } else if (g < 3072) {
        int i = g - 2048, k = i >> 8, j = i & 255;
        pw[g] = pk(W1[k * 256 + j], W1[(k + 4) * 256 + j]);
    } else if (g < 7168) {
        int i = g - 3072, kk = i >> 6, e = i & 63;
        pw[g] = pk(W2[kk * 64 + e], W2[(kk + 64) * 64 + e]);
    } else if (g < 11264) {
        int i = g - 7168, kk = i >> 6, e = i & 63;
        pw[g] = pk(W2[(kk + 128) * 64 + e], W2[(kk + 192) * 64 + e]);
    }
}

__global__ __launch_bounds__(256, 2)
void qtb_main(const float* __restrict__ x,
              const float* __restrict__ th_a,
              const float* __restrict__ bc,
              const float* __restrict__ g1,
              const float* __restrict__ be1,
              const float* __restrict__ th_f,
              const float* __restrict__ b1,
              const float* __restrict__ b2,
              const float* __restrict__ g2,
              const float* __restrict__ be2,
              const int* __restrict__ pw,
              float* __restrict__ out)
{
    const int lane = threadIdx.x & 63;
    const int wv   = threadIdx.x >> 6;
    const int w    = lane & 7;
    const int gb   = lane & ~7;
    const int tok0 = (blockIdx.x * 4 + wv) * 2;   // 2 tokens per wave

    const int* pWc  = pw;
    const int* pW1  = pw + 2048;
    const int* pW2a = pw + 3072;
    const int* pW2b = pw + 7168;

    // x loads first (independent, issue early)
    float xr[2];
#pragma unroll
    for (int t = 0; t < 2; ++t) xr[t] = x[(tok0 + t) * 64 + lane];

    // thetas (t2, t5 are RZ -> cannot affect <Z>)
    const float C0a = __cosf(th_a[0]);
    const float T1a = th_a[1];
    const float C3a = __cosf(th_a[3]);
    const float T4a = th_a[4];
    const float C0f = __cosf(th_f[0]);
    const float T1f = th_f[1];
    const float C3f = __cosf(th_f[3]);
    const float T4f = th_f[4];

    const float bcL = bc[lane], g1L = g1[lane], be1L = be1[lane];
    const float b2L = b2[lane], g2L = g2[lane], be2L = be2[lane];
    float b1L[4];
#pragma unroll
    for (int r = 0; r < 4; ++r) b1L[r] = b1[r * 64 + lane];

    // ---- quantum attention expectations (closed form, in registers) ----
    const float dA = (w == 2) ? T4a : ((w == 3) ? T1a : 0.0f);
    int zp[2];
#pragma unroll
    for (int t = 0; t < 2; ++t) {
        float c  = __cosf(xr[t] + dA);
        float c0 = __shfl(c, gb, 64);       // cos(a0) of this 8-group
        float c1 = __shfl(c, gb + 1, 64);   // cos(a1)
        float zz = c * ((w == 0) ? C0a : ((w == 6) ? C3a : 1.0f));
        if (w == 4) zz = c * c1;
        if (w == 7) zz = C0a * c0 * c;
        // pack (z[lane], z[lane^32]) so readlane at q<32 yields (z[q], z[q+32])
        zp[t] = pk(zz, __shfl_xor(zz, 32, 64));
    }

    // ---- attn = Z @ Wc + bc : readlane + dot2, K=64 as 32 pairs ----
    float acc[2] = {bcL, bcL};
#pragma unroll 8
    for (int q = 0; q < 32; ++q) {
        int wq = pWc[q * 64 + lane];
        acc[0] = fdot2i(rl_i(zp[0], q), wq, acc[0]);
        acc[1] = fdot2i(rl_i(zp[1], q), wq, acc[1]);
    }

    // ---- y = LN(x + attn) ----
    float y[2];
#pragma unroll
    for (int t = 0; t < 2; ++t) {
        float v = xr[t] + acc[t];
        float s = v, s2 = v * v;
        wave_sum2(s, s2);
        float m   = s * 0.015625f;
        float var = s2 * 0.015625f - m * m;
        y[t] = (v - m) * rsqrtf(var + 1e-5f) * g1L + be1L;
    }

    // ---- ffn quantum gate (on y[:, :8]) + h = relu(QF @ W1 + b1) ----
    const float dF = (w == 2) ? T4f : ((w == 3) ? T1f : 0.0f);
    float h[2][4];
#pragma unroll
    for (int t = 0; t < 2; ++t) {
        float cy = __cosf(y[t] + dF);        // meaningful on lanes 0..7
        float c0 = rl_f(cy, 0);
        float c1 = rl_f(cy, 1);
        float qz = cy * ((w == 0) ? C0f : ((w == 6) ? C3f : 1.0f));
        if (w == 4) qz = cy * c1;
        if (w == 7) qz = C0f * c0 * cy;
        // pairs (k, k+4) to match pW1
        int qp0 = pk(rl_f(qz, 0), rl_f(qz, 4));
        int qp1 = pk(rl_f(qz, 1), rl_f(qz, 5));
        int qp2 = pk(rl_f(qz, 2), rl_f(qz, 6));
        int qp3 = pk(rl_f(qz, 3), rl_f(qz, 7));
#pragma unroll
        for (int r = 0; r < 4; ++r) {
            float a = b1L[r];
            a = fdot2i(qp0, pW1[0 * 256 + r * 64 + lane], a);
            a = fdot2i(qp1, pW1[1 * 256 + r * 64 + lane], a);
            a = fdot2i(qp2, pW1[2 * 256 + r * 64 + lane], a);
            a = fdot2i(qp3, pW1[3 * 256 + r * 64 + lane], a);
            h[t][r] = fmaxf(a, 0.0f);
        }
    }

    // ---- ffn2 = H @ W2 + b2 (K=256 as 64 x 2 pairs) ----
    float a2[2] = {b2L, b2L};
    int hp0[2], hp1[2];
#pragma unroll
    for (int t = 0; t < 2; ++t) {
        hp0[t] = pk(h[t][0], h[t][1]);   // (h[j], h[j+64])   at lane j
        hp1[t] = pk(h[t][2], h[t][3]);   // (h[j+128], h[j+192])
    }
#pragma unroll 8
    for (int kk = 0; kk < 64; ++kk) {
        int wa = pW2a[kk * 64 + lane];
        int wb = pW2b[kk * 64 + lane];
        a2[0] = fdot2i(rl_i(hp0[0], kk), wa, a2[0]);
        a2[0] = fdot2i(rl_i(hp1[0], kk), wb, a2[0]);
        a2[1] = fdot2i(rl_i(hp0[1], kk), wa, a2[1]);
        a2[1] = fdot2i(rl_i(hp1[1], kk), wb, a2[1]);
    }

    // ---- out = LN(y + ffn) ----
#pragma unroll
    for (int t = 0; t < 2; ++t) {
        float v = y[t] + a2[t];
        float s = v, s2 = v * v;
        wave_sum2(s, s2);
        float m   = s * 0.015625f;
        float var = s2 * 0.015625f - m * m;
        out[(tok0 + t) * 64 + lane] = (v - m) * rsqrtf(var + 1e-5f) * g2L + be2L;
    }
}

extern "C" void kernel_launch(void* const* d_in, const int* in_sizes, int n_in,
                              void* d_out, int out_size, void* d_ws, size_t ws_size,
                              hipStream_t stream)
{
    const float* x   = (const float*)d_in[0];
    const float* at  = (const float*)d_in[1];
    const float* Wc  = (const float*)d_in[2];
    const float* bcp = (const float*)d_in[3];
    const float* g1  = (const float*)d_in[4];
    const float* be1 = (const float*)d_in[5];
    const float* ft  = (const float*)d_in[6];
    const float* W1  = (const float*)d_in[7];
    const float* b1  = (const float*)d_in[8];
    const float* W2  = (const float*)d_in[9];
    const float* b2  = (const float*)d_in[10];
    const float* g2  = (const float*)d_in[11];
    const float* be2 = (const float*)d_in[12];
    float* out = (float*)d_out;
    int* pw = (int*)d_ws;   // needs 45056 B

    qtb_pack<<<44, 256, 0, stream>>>(Wc, W1, W2, pw);
    // 4096 tokens = 512 blocks x 4 waves x 2 tokens; 2 blocks/CU
    qtb_main<<<512, 256, 0, stream>>>(x, at, bcp, g1, be1, ft,
                                      b1, b2, g2, be2, pw, out);
}

// Round 5
// 14.985 us; speedup vs baseline: 1.2252x; 1.2252x over previous
//
#include <hip/hip_runtime.h>

// Fused quantum-transformer block, v5: single dispatch, zero-LDS, zero-barrier.
// 512 blocks x 256 threads (2 blocks/CU, 2 waves/SIMD), 2 tokens per wave.
//
// Closed-form circuit (verified round 1): OPS = ry(0,t0) rx(3,t1) rz(5,t2)
// cx(1,4) ry(6,t3) rx(2,t4) cx(0,7) rz(4,t5) on RX(a_w)-encoded product state.
//   z0 = cos(t0) cos(a0)          z4 = cos(a1) cos(a4)
//   z1 = cos(a1)                  z5 = cos(a5)
//   z2 = cos(a2 + t4)             z6 = cos(t3) cos(a6)
//   z3 = cos(a3 + t1)             z7 = cos(t0) cos(a0) cos(a7)
//
// Lane = embedding index e. Activation broadcast via v_readlane (per-SIMD
// VALU), weights streamed from global (L1/L2-resident, same across blocks).
// ffn2 (K=256, dominant GEMV) uses in-register fp16 pairs + v_dot2_f32_f16.

typedef _Float16 h2f __attribute__((ext_vector_type(2)));

__device__ __forceinline__ int pk(float a, float b) {
    return __builtin_bit_cast(int, __builtin_amdgcn_cvt_pkrtz(a, b));
}
__device__ __forceinline__ float fdot2i(int a, int b, float c) {
    return __builtin_amdgcn_fdot2(__builtin_bit_cast(h2f, a),
                                  __builtin_bit_cast(h2f, b), c, false);
}
__device__ __forceinline__ float rl_f(float v, int l) {
    return __int_as_float(__builtin_amdgcn_readlane(__float_as_int(v), l));
}
__device__ __forceinline__ int rl_i(int v, int l) {
    return __builtin_amdgcn_readlane(v, l);
}
__device__ __forceinline__ void wave_sum2(float& a, float& b) {
#pragma unroll
    for (int m = 32; m > 0; m >>= 1) {
        a += __shfl_xor(a, m, 64);
        b += __shfl_xor(b, m, 64);
    }
}

__global__ __launch_bounds__(256, 2)
void qtb_fused5(const float* __restrict__ x,
                const float* __restrict__ th_a,
                const float* __restrict__ Wc,
                const float* __restrict__ bc,
                const float* __restrict__ g1,
                const float* __restrict__ be1,
                const float* __restrict__ th_f,
                const float* __restrict__ W1,
                const float* __restrict__ b1,
                const float* __restrict__ W2,
                const float* __restrict__ b2,
                const float* __restrict__ g2,
                const float* __restrict__ be2,
                float* __restrict__ out)
{
    const int lane = threadIdx.x & 63;
    const int wv   = threadIdx.x >> 6;
    const int w    = lane & 7;
    const int gb   = lane & ~7;
    const int tok0 = (blockIdx.x * 4 + wv) * 2;   // 2 tokens per wave

    // x loads first (independent, issue early)
    float xr[2];
#pragma unroll
    for (int t = 0; t < 2; ++t) xr[t] = x[(tok0 + t) * 64 + lane];

    // thetas (t2, t5 are RZ — cannot affect <Z>)
    const float C0a = __cosf(th_a[0]);
    const float T1a = th_a[1];
    const float C3a = __cosf(th_a[3]);
    const float T4a = th_a[4];
    const float C0f = __cosf(th_f[0]);
    const float T1f = th_f[1];
    const float C3f = __cosf(th_f[3]);
    const float T4f = th_f[4];

    const float bcL = bc[lane], g1L = g1[lane], be1L = be1[lane];
    const float b2L = b2[lane], g2L = g2[lane], be2L = be2[lane];
    float b1L[4];
#pragma unroll
    for (int r = 0; r < 4; ++r) b1L[r] = b1[r * 64 + lane];

    // ---- quantum attention expectations (closed form, in registers) ----
    const float dA = (w == 2) ? T4a : ((w == 3) ? T1a : 0.0f);
    float z[2];
#pragma unroll
    for (int t = 0; t < 2; ++t) {
        float c  = __cosf(xr[t] + dA);
        float c0 = __shfl(c, gb, 64);       // cos(a0) of this 8-group
        float c1 = __shfl(c, gb + 1, 64);   // cos(a1)
        float zz = c * ((w == 0) ? C0a : ((w == 6) ? C3a : 1.0f));
        if (w == 4) zz = c * c1;
        if (w == 7) zz = C0a * c0 * c;
        z[t] = zz;
    }

    // ---- attn = Z @ Wc + bc : readlane-broadcast GEMV (K=64) ----
    float acc[2] = {bcL, bcL};
#pragma unroll 8
    for (int q = 0; q < 64; ++q) {
        float wq = Wc[q * 64 + lane];        // coalesced, L1/L2-resident
        acc[0] = fmaf(rl_f(z[0], q), wq, acc[0]);
        acc[1] = fmaf(rl_f(z[1], q), wq, acc[1]);
    }

    // ---- y = LN(x + attn) ----
    float y[2];
#pragma unroll
    for (int t = 0; t < 2; ++t) {
        float v = xr[t] + acc[t];
        float s = v, s2 = v * v;
        wave_sum2(s, s2);
        float m   = s * 0.015625f;
        float var = s2 * 0.015625f - m * m;
        y[t] = (v - m) * rsqrtf(var + 1e-5f) * g1L + be1L;
    }

    // ---- ffn quantum gate (on y[:,:8]) + h = relu(QF @ W1 + b1) in regs ----
    float w1r[4][8];
#pragma unroll
    for (int k = 0; k < 8; ++k)
#pragma unroll
        for (int r = 0; r < 4; ++r) w1r[r][k] = W1[k * 256 + r * 64 + lane];

    const float dF = (w == 2) ? T4f : ((w == 3) ? T1f : 0.0f);
    float h[2][4];
#pragma unroll
    for (int t = 0; t < 2; ++t) {
        float cy = __cosf(y[t] + dF);        // meaningful on lanes 0..7
        float c0 = rl_f(cy, 0);
        float c1 = rl_f(cy, 1);
        float qz = cy * ((w == 0) ? C0f : ((w == 6) ? C3f : 1.0f));
        if (w == 4) qz = cy * c1;
        if (w == 7) qz = C0f * c0 * cy;
        float qf[8];
#pragma unroll
        for (int k = 0; k < 8; ++k) qf[k] = rl_f(qz, k);
#pragma unroll
        for (int r = 0; r < 4; ++r) {
            float a = b1L[r];
#pragma unroll
            for (int k = 0; k < 8; ++k) a = fmaf(qf[k], w1r[r][k], a);
            h[t][r] = fmaxf(a, 0.0f);
        }
    }

    // ---- ffn2 = H @ W2 + b2 (K=256), pairs (j, j+64) via v_dot2_f32_f16 ----
    float a2[2] = {b2L, b2L};
    int hp0[2], hp1[2];
#pragma unroll
    for (int t = 0; t < 2; ++t) {
        hp0[t] = pk(h[t][0], h[t][1]);   // readlane at kk -> (h[kk], h[kk+64])
        hp1[t] = pk(h[t][2], h[t][3]);   // (h[kk+128], h[kk+192])
    }
#pragma unroll 8
    for (int kk = 0; kk < 64; ++kk) {
        float wa = W2[(kk      ) * 64 + lane];
        float wb = W2[(kk +  64) * 64 + lane];
        float wc = W2[(kk + 128) * 64 + lane];
        float wd = W2[(kk + 192) * 64 + lane];
        int wp0 = pk(wa, wb);
        int wp1 = pk(wc, wd);
        a2[0] = fdot2i(rl_i(hp0[0], kk), wp0, a2[0]);
        a2[0] = fdot2i(rl_i(hp1[0], kk), wp1, a2[0]);
        a2[1] = fdot2i(rl_i(hp0[1], kk), wp0, a2[1]);
        a2[1] = fdot2i(rl_i(hp1[1], kk), wp1, a2[1]);
    }

    // ---- out = LN(y + ffn) ----
#pragma unroll
    for (int t = 0; t < 2; ++t) {
        float v = y[t] + a2[t];
        float s = v, s2 = v * v;
        wave_sum2(s, s2);
        float m   = s * 0.015625f;
        float var = s2 * 0.015625f - m * m;
        out[(tok0 + t) * 64 + lane] = (v - m) * rsqrtf(var + 1e-5f) * g2L + be2L;
    }
}

extern "C" void kernel_launch(void* const* d_in, const int* in_sizes, int n_in,
                              void* d_out, int out_size, void* d_ws, size_t ws_size,
                              hipStream_t stream)
{
    const float* x   = (const float*)d_in[0];
    const float* at  = (const float*)d_in[1];
    const float* Wc  = (const float*)d_in[2];
    const float* bcp = (const float*)d_in[3];
    const float* g1  = (const float*)d_in[4];
    const float* be1 = (const float*)d_in[5];
    const float* ft  = (const float*)d_in[6];
    const float* W1  = (const float*)d_in[7];
    const float* b1  = (const float*)d_in[8];
    const float* W2  = (const float*)d_in[9];
    const float* b2  = (const float*)d_in[10];
    const float* g2  = (const float*)d_in[11];
    const float* be2 = (const float*)d_in[12];
    float* out = (float*)d_out;

    // 4096 tokens = 512 blocks x 4 waves x 2 tokens; single dispatch,
    // no LDS, no barriers, 2 blocks/CU.
    qtb_fused5<<<512, 256, 0, stream>>>(x, at, Wc, bcp, g1, be1, ft,
                                        W1, b1, W2, b2, g2, be2, out);
}

// Round 6
// 13.444 us; speedup vs baseline: 1.3656x; 1.1146x over previous
//
#include <hip/hip_runtime.h>

// Fused quantum-transformer block, v6: single dispatch, per-block fp16 weight
// staging in LDS (44 KB), readlane activation broadcast, v_dot2_f32_f16 GEMVs.
// 512 blocks x 256 threads (2 blocks/CU, 2 waves/SIMD), 2 tokens per wave.
//
// Closed-form circuit (verified round 1): OPS = ry(0,t0) rx(3,t1) rz(5,t2)
// cx(1,4) ry(6,t3) rx(2,t4) cx(0,7) rz(4,t5) on RX(a_w)-encoded product state.
//   z0 = cos(t0) cos(a0)          z4 = cos(a1) cos(a4)
//   z1 = cos(a1)                  z5 = cos(a5)
//   z2 = cos(a2 + t4)             z6 = cos(t3) cos(a6)
//   z3 = cos(a3 + t1)             z7 = cos(t0) cos(a0) cos(a7)
//
// LDS layout (fp16 pair words, proven numerically safe in v4):
//   sWc[q2*64+e] : int2 = ( pk(Wc[2q2][e],   Wc[2q2+32][e]),
//                           pk(Wc[2q2+1][e], Wc[2q2+33][e]) )        8 KB
//   sW1[j]       : int4 = ( pk(W1[k][j], W1[k+4][j]) for k=0..3 )    4 KB
//   sW2[kk2*64+e]: int4 = ( A(2kk2), A(2kk2+1), B(2kk2), B(2kk2+1) ) 32 KB
//     where A(kk) = pk(W2[kk][e], W2[kk+64][e]),
//           B(kk) = pk(W2[kk+128][e], W2[kk+192][e])

typedef _Float16 h2f __attribute__((ext_vector_type(2)));

__device__ __forceinline__ int pk(float a, float b) {
    return __builtin_bit_cast(int, __builtin_amdgcn_cvt_pkrtz(a, b));
}
__device__ __forceinline__ float fdot2i(int a, int b, float c) {
    return __builtin_amdgcn_fdot2(__builtin_bit_cast(h2f, a),
                                  __builtin_bit_cast(h2f, b), c, false);
}
__device__ __forceinline__ float rl_f(float v, int l) {
    return __int_as_float(__builtin_amdgcn_readlane(__float_as_int(v), l));
}
__device__ __forceinline__ int rl_i(int v, int l) {
    return __builtin_amdgcn_readlane(v, l);
}
__device__ __forceinline__ void wave_sum2(float& a, float& b) {
#pragma unroll
    for (int m = 32; m > 0; m >>= 1) {
        a += __shfl_xor(a, m, 64);
        b += __shfl_xor(b, m, 64);
    }
}

__global__ __launch_bounds__(256, 2)
void qtb_fused6(const float* __restrict__ x,
                const float* __restrict__ th_a,
                const float* __restrict__ Wc,
                const float* __restrict__ bc,
                const float* __restrict__ g1,
                const float* __restrict__ be1,
                const float* __restrict__ th_f,
                const float* __restrict__ W1,
                const float* __restrict__ b1,
                const float* __restrict__ W2,
                const float* __restrict__ b2,
                const float* __restrict__ g2,
                const float* __restrict__ be2,
                float* __restrict__ out)
{
    __shared__ __align__(16) int2 sWc[16 * 64];   //  8 KB
    __shared__ __align__(16) int4 sW1[256];       //  4 KB
    __shared__ __align__(16) int4 sW2[32 * 64];   // 32 KB

    const int tid  = threadIdx.x;
    const int lane = tid & 63;
    const int wv   = tid >> 6;
    const int w    = lane & 7;
    const int gb   = lane & ~7;
    const int tok0 = (blockIdx.x * 4 + wv) * 2;   // 2 tokens per wave

    // ---- stage packed fp16 weights into LDS (coalesced f32 loads) ----
#pragma unroll
    for (int s = 0; s < 4; ++s) {
        int i  = tid + 256 * s;          // i = q2*64 + e
        int q2 = i >> 6, e = i & 63;
        const float* b = Wc + e;
        sWc[i] = make_int2(pk(b[(2 * q2) * 64],     b[(2 * q2 + 32) * 64]),
                           pk(b[(2 * q2 + 1) * 64], b[(2 * q2 + 33) * 64]));
    }
    {
        int j = tid;
        sW1[j] = make_int4(pk(W1[0 * 256 + j], W1[4 * 256 + j]),
                           pk(W1[1 * 256 + j], W1[5 * 256 + j]),
                           pk(W1[2 * 256 + j], W1[6 * 256 + j]),
                           pk(W1[3 * 256 + j], W1[7 * 256 + j]));
    }
#pragma unroll
    for (int s = 0; s < 8; ++s) {
        int i   = tid + 256 * s;         // i = kk2*64 + e
        int kk2 = i >> 6, e = i & 63;
        const float* b = W2 + e;
        int kk = 2 * kk2;
        sW2[i] = make_int4(pk(b[kk * 64],         b[(kk + 64) * 64]),
                           pk(b[(kk + 1) * 64],   b[(kk + 65) * 64]),
                           pk(b[(kk + 128) * 64], b[(kk + 192) * 64]),
                           pk(b[(kk + 129) * 64], b[(kk + 193) * 64]));
    }

    // independent global loads issued while staging is in flight
    float xr[2];
#pragma unroll
    for (int t = 0; t < 2; ++t) xr[t] = x[(tok0 + t) * 64 + lane];

    const float C0a = __cosf(th_a[0]);
    const float T1a = th_a[1];
    const float C3a = __cosf(th_a[3]);
    const float T4a = th_a[4];
    const float C0f = __cosf(th_f[0]);
    const float T1f = th_f[1];
    const float C3f = __cosf(th_f[3]);
    const float T4f = th_f[4];

    const float bcL = bc[lane], g1L = g1[lane], be1L = be1[lane];
    const float b2L = b2[lane], g2L = g2[lane], be2L = be2[lane];
    float b1L[4];
#pragma unroll
    for (int r = 0; r < 4; ++r) b1L[r] = b1[r * 64 + lane];

    // ---- quantum attention expectations (closed form, in registers) ----
    const float dA = (w == 2) ? T4a : ((w == 3) ? T1a : 0.0f);
    int zp[2];
#pragma unroll
    for (int t = 0; t < 2; ++t) {
        float c  = __cosf(xr[t] + dA);
        float c0 = __shfl(c, gb, 64);       // cos(a0) of this 8-group
        float c1 = __shfl(c, gb + 1, 64);   // cos(a1)
        float zz = c * ((w == 0) ? C0a : ((w == 6) ? C3a : 1.0f));
        if (w == 4) zz = c * c1;
        if (w == 7) zz = C0a * c0 * c;
        // readlane at q < 32 yields (z[q], z[q+32])
        zp[t] = pk(zz, __shfl_xor(zz, 32, 64));
    }

    __syncthreads();   // staging complete

    // ---- attn = Z @ Wc + bc : K=64 as 32 fp16-pair words, int2 reads ----
    float acc[2] = {bcL, bcL};
#pragma unroll 4
    for (int q2 = 0; q2 < 16; ++q2) {
        int2 wq = sWc[q2 * 64 + lane];
        int q = 2 * q2;
        acc[0] = fdot2i(rl_i(zp[0], q),     wq.x, acc[0]);
        acc[1] = fdot2i(rl_i(zp[1], q),     wq.x, acc[1]);
        acc[0] = fdot2i(rl_i(zp[0], q + 1), wq.y, acc[0]);
        acc[1] = fdot2i(rl_i(zp[1], q + 1), wq.y, acc[1]);
    }

    // ---- y = LN(x + attn) ----
    float y[2];
#pragma unroll
    for (int t = 0; t < 2; ++t) {
        float v = xr[t] + acc[t];
        float s = v, s2 = v * v;
        wave_sum2(s, s2);
        float m   = s * 0.015625f;
        float var = s2 * 0.015625f - m * m;
        y[t] = (v - m) * rsqrtf(var + 1e-5f) * g1L + be1L;
    }

    // ---- ffn quantum gate (y[:, :8]) + h = relu(QF @ W1 + b1) ----
    int4 w1q[4];
#pragma unroll
    for (int r = 0; r < 4; ++r) w1q[r] = sW1[r * 64 + lane];

    const float dF = (w == 2) ? T4f : ((w == 3) ? T1f : 0.0f);
    float h[2][4];
#pragma unroll
    for (int t = 0; t < 2; ++t) {
        float cy = __cosf(y[t] + dF);        // meaningful on lanes 0..7
        float c0 = rl_f(cy, 0);
        float c1 = rl_f(cy, 1);
        float qz = cy * ((w == 0) ? C0f : ((w == 6) ? C3f : 1.0f));
        if (w == 4) qz = cy * c1;
        if (w == 7) qz = C0f * c0 * cy;
        int qp0 = pk(rl_f(qz, 0), rl_f(qz, 4));   // pairs (k, k+4)
        int qp1 = pk(rl_f(qz, 1), rl_f(qz, 5));
        int qp2 = pk(rl_f(qz, 2), rl_f(qz, 6));
        int qp3 = pk(rl_f(qz, 3), rl_f(qz, 7));
#pragma unroll
        for (int r = 0; r < 4; ++r) {
            float a = b1L[r];
            a = fdot2i(qp0, w1q[r].x, a);
            a = fdot2i(qp1, w1q[r].y, a);
            a = fdot2i(qp2, w1q[r].z, a);
            a = fdot2i(qp3, w1q[r].w, a);
            h[t][r] = fmaxf(a, 0.0f);
        }
    }

    // ---- ffn2 = H @ W2 + b2 : K=256 as 32 int4 reads ----
    float a2[2] = {b2L, b2L};
    int hp0[2], hp1[2];
#pragma unroll
    for (int t = 0; t < 2; ++t) {
        hp0[t] = pk(h[t][0], h[t][1]);   // readlane at kk -> (h[kk], h[kk+64])
        hp1[t] = pk(h[t][2], h[t][3]);   // (h[kk+128], h[kk+192])
    }
#pragma unroll 4
    for (int kk2 = 0; kk2 < 32; ++kk2) {
        int4 w4 = sW2[kk2 * 64 + lane];
        int kk = 2 * kk2;
        a2[0] = fdot2i(rl_i(hp0[0], kk),     w4.x, a2[0]);
        a2[0] = fdot2i(rl_i(hp1[0], kk),     w4.z, a2[0]);
        a2[1] = fdot2i(rl_i(hp0[1], kk),     w4.x, a2[1]);
        a2[1] = fdot2i(rl_i(hp1[1], kk),     w4.z, a2[1]);
        a2[0] = fdot2i(rl_i(hp0[0], kk + 1), w4.y, a2[0]);
        a2[0] = fdot2i(rl_i(hp1[0], kk + 1), w4.w, a2[0]);
        a2[1] = fdot2i(rl_i(hp0[1], kk + 1), w4.y, a2[1]);
        a2[1] = fdot2i(rl_i(hp1[1], kk + 1), w4.w, a2[1]);
    }

    // ---- out = LN(y + ffn) ----
#pragma unroll
    for (int t = 0; t < 2; ++t) {
        float v = y[t] + a2[t];
        float s = v, s2 = v * v;
        wave_sum2(s, s2);
        float m   = s * 0.015625f;
        float var = s2 * 0.015625f - m * m;
        out[(tok0 + t) * 64 + lane] = (v - m) * rsqrtf(var + 1e-5f) * g2L + be2L;
    }
}

extern "C" void kernel_launch(void* const* d_in, const int* in_sizes, int n_in,
                              void* d_out, int out_size, void* d_ws, size_t ws_size,
                              hipStream_t stream)
{
    const float* x   = (const float*)d_in[0];
    const float* at  = (const float*)d_in[1];
    const float* Wc  = (const float*)d_in[2];
    const float* bcp = (const float*)d_in[3];
    const float* g1  = (const float*)d_in[4];
    const float* be1 = (const float*)d_in[5];
    const float* ft  = (const float*)d_in[6];
    const float* W1  = (const float*)d_in[7];
    const float* b1  = (const float*)d_in[8];
    const float* W2  = (const float*)d_in[9];
    const float* b2  = (const float*)d_in[10];
    const float* g2  = (const float*)d_in[11];
    const float* be2 = (const float*)d_in[12];
    float* out = (float*)d_out;

    // 4096 tokens = 512 blocks x 4 waves x 2 tokens; single dispatch,
    // 44 KB LDS staged fp16 weights, one barrier, 2 blocks/CU.
    qtb_fused6<<<512, 256, 0, stream>>>(x, at, Wc, bcp, g1, be1, ft,
                                        W1, b1, W2, b2, g2, be2, out);
}

// Round 7
// 12.892 us; speedup vs baseline: 1.4241x; 1.0428x over previous
//
#include <hip/hip_runtime.h>

// Fused quantum-transformer block, v7: single dispatch, weights staged ONCE
// per CU (256 blocks x 512 threads = 1 block/CU, 8 waves, 2 waves/SIMD),
// float4-vectorized fp16-pair staging into LDS, readlane + v_dot2_f32_f16.
//
// Closed-form circuit (verified round 1): OPS = ry(0,t0) rx(3,t1) rz(5,t2)
// cx(1,4) ry(6,t3) rx(2,t4) cx(0,7) rz(4,t5) on RX(a_w)-encoded product state.
//   z0 = cos(t0) cos(a0)          z4 = cos(a1) cos(a4)
//   z1 = cos(a1)                  z5 = cos(a5)
//   z2 = cos(a2 + t4)             z6 = cos(t3) cos(a6)
//   z3 = cos(a3 + t1)             z7 = cos(t0) cos(a0) cos(a7)
//
// LDS layout (fp16 pair words, identical semantics to v6 = proven safe):
//   sWc[q2*64+e] : int2 = ( pk(Wc[2q2][e],   Wc[2q2+32][e]),
//                           pk(Wc[2q2+1][e], Wc[2q2+33][e]) )        8 KB
//   sW1[j]       : int4 = ( pk(W1[k][j], W1[k+4][j]) for k=0..3 )    4 KB
//   sW2[kk2*64+e]: int4 = ( A(2kk2), A(2kk2+1), B(2kk2), B(2kk2+1) ) 32 KB
//     where A(kk) = pk(W2[kk][e], W2[kk+64][e]),
//           B(kk) = pk(W2[kk+128][e], W2[kk+192][e])

typedef _Float16 h2f __attribute__((ext_vector_type(2)));

__device__ __forceinline__ int pk(float a, float b) {
    return __builtin_bit_cast(int, __builtin_amdgcn_cvt_pkrtz(a, b));
}
__device__ __forceinline__ float fdot2i(int a, int b, float c) {
    return __builtin_amdgcn_fdot2(__builtin_bit_cast(h2f, a),
                                  __builtin_bit_cast(h2f, b), c, false);
}
__device__ __forceinline__ float rl_f(float v, int l) {
    return __int_as_float(__builtin_amdgcn_readlane(__float_as_int(v), l));
}
__device__ __forceinline__ int rl_i(int v, int l) {
    return __builtin_amdgcn_readlane(v, l);
}
__device__ __forceinline__ void wave_sum2(float& a, float& b) {
#pragma unroll
    for (int m = 32; m > 0; m >>= 1) {
        a += __shfl_xor(a, m, 64);
        b += __shfl_xor(b, m, 64);
    }
}

__global__ __launch_bounds__(512, 2)
void qtb_fused7(const float* __restrict__ x,
                const float* __restrict__ th_a,
                const float* __restrict__ Wc,
                const float* __restrict__ bc,
                const float* __restrict__ g1,
                const float* __restrict__ be1,
                const float* __restrict__ th_f,
                const float* __restrict__ W1,
                const float* __restrict__ b1,
                const float* __restrict__ W2,
                const float* __restrict__ b2,
                const float* __restrict__ g2,
                const float* __restrict__ be2,
                float* __restrict__ out)
{
    __shared__ __align__(16) int2 sWc[16 * 64];   //  8 KB
    __shared__ __align__(16) int4 sW1[256];       //  4 KB
    __shared__ __align__(16) int4 sW2[32 * 64];   // 32 KB

    const int tid  = threadIdx.x;                 // 0..511
    const int lane = tid & 63;
    const int wv   = tid >> 6;                    // 0..7
    const int w    = lane & 7;
    const int gb   = lane & ~7;
    const int tok0 = (blockIdx.x * 8 + wv) * 2;   // 2 tokens per wave

    // ---- stage packed fp16 weights into LDS, float4 global loads ----
    // W2: every thread one task (32 kk2 x 16 e-groups = 512 tasks)
    {
        int kk2 = tid >> 4;              // 0..31
        int e0  = (tid & 15) * 4;
        int kk  = 2 * kk2;
        const float* b = W2 + e0;
        float4 rA0 = *(const float4*)&b[(kk      ) * 64];
        float4 rA1 = *(const float4*)&b[(kk +   1) * 64];
        float4 rB0 = *(const float4*)&b[(kk +  64) * 64];
        float4 rB1 = *(const float4*)&b[(kk +  65) * 64];
        float4 rC0 = *(const float4*)&b[(kk + 128) * 64];
        float4 rC1 = *(const float4*)&b[(kk + 129) * 64];
        float4 rD0 = *(const float4*)&b[(kk + 192) * 64];
        float4 rD1 = *(const float4*)&b[(kk + 193) * 64];
        int4* dst = &sW2[kk2 * 64 + e0];
        dst[0] = make_int4(pk(rA0.x, rB0.x), pk(rA1.x, rB1.x),
                           pk(rC0.x, rD0.x), pk(rC1.x, rD1.x));
        dst[1] = make_int4(pk(rA0.y, rB0.y), pk(rA1.y, rB1.y),
                           pk(rC0.y, rD0.y), pk(rC1.y, rD1.y));
        dst[2] = make_int4(pk(rA0.z, rB0.z), pk(rA1.z, rB1.z),
                           pk(rC0.z, rD0.z), pk(rC1.z, rD1.z));
        dst[3] = make_int4(pk(rA0.w, rB0.w), pk(rA1.w, rB1.w),
                           pk(rC0.w, rD0.w), pk(rC1.w, rD1.w));
    }
    // Wc: threads 0..255 (16 q2 x 16 e-groups)
    if (tid < 256) {
        int q2 = tid >> 4;               // 0..15
        int e0 = (tid & 15) * 4;
        const float* b = Wc + e0;
        float4 r0 = *(const float4*)&b[(2 * q2     ) * 64];
        float4 r1 = *(const float4*)&b[(2 * q2 +  1) * 64];
        float4 r2 = *(const float4*)&b[(2 * q2 + 32) * 64];
        float4 r3 = *(const float4*)&b[(2 * q2 + 33) * 64];
        int4* dst = (int4*)&sWc[q2 * 64 + e0];
        dst[0] = make_int4(pk(r0.x, r2.x), pk(r1.x, r3.x),
                           pk(r0.y, r2.y), pk(r1.y, r3.y));
        dst[1] = make_int4(pk(r0.z, r2.z), pk(r1.z, r3.z),
                           pk(r0.w, r2.w), pk(r1.w, r3.w));
    } else if (tid < 320) {
        // W1: threads 256..319 (64 j-groups)
        int j0 = (tid - 256) * 4;
        float4 r[8];
#pragma unroll
        for (int k = 0; k < 8; ++k) r[k] = *(const float4*)&W1[k * 256 + j0];
        const float* f = (const float*)r;   // f[k*4 + j]
        int4* dst = &sW1[j0];
#pragma unroll
        for (int j = 0; j < 4; ++j)
            dst[j] = make_int4(pk(f[0 * 4 + j], f[4 * 4 + j]),
                               pk(f[1 * 4 + j], f[5 * 4 + j]),
                               pk(f[2 * 4 + j], f[6 * 4 + j]),
                               pk(f[3 * 4 + j], f[7 * 4 + j]));
    }

    // independent global loads issued while staging is in flight
    float xr[2];
#pragma unroll
    for (int t = 0; t < 2; ++t) xr[t] = x[(tok0 + t) * 64 + lane];

    const float C0a = __cosf(th_a[0]);
    const float T1a = th_a[1];
    const float C3a = __cosf(th_a[3]);
    const float T4a = th_a[4];
    const float C0f = __cosf(th_f[0]);
    const float T1f = th_f[1];
    const float C3f = __cosf(th_f[3]);
    const float T4f = th_f[4];

    const float bcL = bc[lane], g1L = g1[lane], be1L = be1[lane];
    const float b2L = b2[lane], g2L = g2[lane], be2L = be2[lane];
    float b1L[4];
#pragma unroll
    for (int r = 0; r < 4; ++r) b1L[r] = b1[r * 64 + lane];

    // ---- quantum attention expectations (closed form, in registers) ----
    const float dA = (w == 2) ? T4a : ((w == 3) ? T1a : 0.0f);
    int zp[2];
#pragma unroll
    for (int t = 0; t < 2; ++t) {
        float c  = __cosf(xr[t] + dA);
        float c0 = __shfl(c, gb, 64);       // cos(a0) of this 8-group
        float c1 = __shfl(c, gb + 1, 64);   // cos(a1)
        float zz = c * ((w == 0) ? C0a : ((w == 6) ? C3a : 1.0f));
        if (w == 4) zz = c * c1;
        if (w == 7) zz = C0a * c0 * c;
        // readlane at q < 32 yields (z[q], z[q+32])
        zp[t] = pk(zz, __shfl_xor(zz, 32, 64));
    }

    __syncthreads();   // staging complete

    // ---- attn = Z @ Wc + bc : K=64 as 32 fp16-pair words, int2 reads ----
    float acc[2] = {bcL, bcL};
#pragma unroll 4
    for (int q2 = 0; q2 < 16; ++q2) {
        int2 wq = sWc[q2 * 64 + lane];
        int q = 2 * q2;
        acc[0] = fdot2i(rl_i(zp[0], q),     wq.x, acc[0]);
        acc[1] = fdot2i(rl_i(zp[1], q),     wq.x, acc[1]);
        acc[0] = fdot2i(rl_i(zp[0], q + 1), wq.y, acc[0]);
        acc[1] = fdot2i(rl_i(zp[1], q + 1), wq.y, acc[1]);
    }

    // ---- y = LN(x + attn) ----
    float y[2];
#pragma unroll
    for (int t = 0; t < 2; ++t) {
        float v = xr[t] + acc[t];
        float s = v, s2 = v * v;
        wave_sum2(s, s2);
        float m   = s * 0.015625f;
        float var = s2 * 0.015625f - m * m;
        y[t] = (v - m) * rsqrtf(var + 1e-5f) * g1L + be1L;
    }

    // ---- ffn quantum gate (y[:, :8]) + h = relu(QF @ W1 + b1) ----
    int4 w1q[4];
#pragma unroll
    for (int r = 0; r < 4; ++r) w1q[r] = sW1[r * 64 + lane];

    const float dF = (w == 2) ? T4f : ((w == 3) ? T1f : 0.0f);
    float h[2][4];
#pragma unroll
    for (int t = 0; t < 2; ++t) {
        float cy = __cosf(y[t] + dF);        // meaningful on lanes 0..7
        float c0 = rl_f(cy, 0);
        float c1 = rl_f(cy, 1);
        float qz = cy * ((w == 0) ? C0f : ((w == 6) ? C3f : 1.0f));
        if (w == 4) qz = cy * c1;
        if (w == 7) qz = C0f * c0 * cy;
        int qp0 = pk(rl_f(qz, 0), rl_f(qz, 4));   // pairs (k, k+4)
        int qp1 = pk(rl_f(qz, 1), rl_f(qz, 5));
        int qp2 = pk(rl_f(qz, 2), rl_f(qz, 6));
        int qp3 = pk(rl_f(qz, 3), rl_f(qz, 7));
#pragma unroll
        for (int r = 0; r < 4; ++r) {
            float a = b1L[r];
            a = fdot2i(qp0, w1q[r].x, a);
            a = fdot2i(qp1, w1q[r].y, a);
            a = fdot2i(qp2, w1q[r].z, a);
            a = fdot2i(qp3, w1q[r].w, a);
            h[t][r] = fmaxf(a, 0.0f);
        }
    }

    // ---- ffn2 = H @ W2 + b2 : K=256 as 32 int4 reads ----
    float a2[2] = {b2L, b2L};
    int hp0[2], hp1[2];
#pragma unroll
    for (int t = 0; t < 2; ++t) {
        hp0[t] = pk(h[t][0], h[t][1]);   // readlane at kk -> (h[kk], h[kk+64])
        hp1[t] = pk(h[t][2], h[t][3]);   // (h[kk+128], h[kk+192])
    }
#pragma unroll 4
    for (int kk2 = 0; kk2 < 32; ++kk2) {
        int4 w4 = sW2[kk2 * 64 + lane];
        int kk = 2 * kk2;
        a2[0] = fdot2i(rl_i(hp0[0], kk),     w4.x, a2[0]);
        a2[0] = fdot2i(rl_i(hp1[0], kk),     w4.z, a2[0]);
        a2[1] = fdot2i(rl_i(hp0[1], kk),     w4.x, a2[1]);
        a2[1] = fdot2i(rl_i(hp1[1], kk),     w4.z, a2[1]);
        a2[0] = fdot2i(rl_i(hp0[0], kk + 1), w4.y, a2[0]);
        a2[0] = fdot2i(rl_i(hp1[0], kk + 1), w4.w, a2[0]);
        a2[1] = fdot2i(rl_i(hp0[1], kk + 1), w4.y, a2[1]);
        a2[1] = fdot2i(rl_i(hp1[1], kk + 1), w4.w, a2[1]);
    }

    // ---- out = LN(y + ffn) ----
#pragma unroll
    for (int t = 0; t < 2; ++t) {
        float v = y[t] + a2[t];
        float s = v, s2 = v * v;
        wave_sum2(s, s2);
        float m   = s * 0.015625f;
        float var = s2 * 0.015625f - m * m;
        out[(tok0 + t) * 64 + lane] = (v - m) * rsqrtf(var + 1e-5f) * g2L + be2L;
    }
}

extern "C" void kernel_launch(void* const* d_in, const int* in_sizes, int n_in,
                              void* d_out, int out_size, void* d_ws, size_t ws_size,
                              hipStream_t stream)
{
    const float* x   = (const float*)d_in[0];
    const float* at  = (const float*)d_in[1];
    const float* Wc  = (const float*)d_in[2];
    const float* bcp = (const float*)d_in[3];
    const float* g1  = (const float*)d_in[4];
    const float* be1 = (const float*)d_in[5];
    const float* ft  = (const float*)d_in[6];
    const float* W1  = (const float*)d_in[7];
    const float* b1  = (const float*)d_in[8];
    const float* W2  = (const float*)d_in[9];
    const float* b2  = (const float*)d_in[10];
    const float* g2  = (const float*)d_in[11];
    const float* be2 = (const float*)d_in[12];
    float* out = (float*)d_out;

    // 4096 tokens = 256 blocks x 8 waves x 2 tokens; single dispatch,
    // 1 block/CU, weights staged once per CU, 44 KB LDS, one barrier.
    qtb_fused7<<<256, 512, 0, stream>>>(x, at, Wc, bcp, g1, be1, ft,
                                        W1, b1, W2, b2, g2, be2, out);
}

// Round 8
// 11.575 us; speedup vs baseline: 1.5862x; 1.1138x over previous
//
#include <hip/hip_runtime.h>

// Fused quantum-transformer block, v8: ffn2 GEMV -> per-block MFMA GEMM.
// 256 blocks x 512 threads (1 block/CU, 8 waves, 2 waves/SIMD), 2 tokens/wave.
// Weights staged once per CU; attn/ffn1 stay readlane+fdot2; ffn2 uses
// mfma_f32_16x16x32_f16 (weights amortized over the block's 16 tokens).
//
// Closed-form circuit (verified round 1): OPS = ry(0,t0) rx(3,t1) rz(5,t2)
// cx(1,4) ry(6,t3) rx(2,t4) cx(0,7) rz(4,t5) on RX(a_w)-encoded product state.
//   z0 = cos(t0) cos(a0)          z4 = cos(a1) cos(a4)
//   z1 = cos(a1)                  z5 = cos(a5)
//   z2 = cos(a2 + t4)             z6 = cos(t3) cos(a6)
//   z3 = cos(a3 + t1)             z7 = cos(t0) cos(a0) cos(a7)
//
// LDS:
//   sWc [q2*64+e] int2 : (pk(Wc[2q2][e],Wc[2q2+32][e]), pk(.. +1 ..))   8 KB
//   sW1 [j]      int4  : (pk(W1[k][j], W1[k+4][j]) k=0..3)              4 KB
//   sW2t[e][k]   f16   : W2 transposed, row-pad 264 (bank decorrelate)  33 KB
//   sH  [tok][c] f16   : ffn1 activations, row-pad 264                   8.3 KB
//   sO  [tok][e] f32   : ffn2 GEMM output, row-pad 66                    4.1 KB

typedef _Float16 h2f  __attribute__((ext_vector_type(2)));
typedef _Float16 f16x8 __attribute__((ext_vector_type(8)));
typedef float    f32x4 __attribute__((ext_vector_type(4)));

__device__ __forceinline__ int pk(float a, float b) {
    return __builtin_bit_cast(int, __builtin_amdgcn_cvt_pkrtz(a, b));
}
__device__ __forceinline__ float fdot2i(int a, int b, float c) {
    return __builtin_amdgcn_fdot2(__builtin_bit_cast(h2f, a),
                                  __builtin_bit_cast(h2f, b), c, false);
}
__device__ __forceinline__ float rl_f(float v, int l) {
    return __int_as_float(__builtin_amdgcn_readlane(__float_as_int(v), l));
}
__device__ __forceinline__ int rl_i(int v, int l) {
    return __builtin_amdgcn_readlane(v, l);
}
__device__ __forceinline__ void wave_sum2(float& a, float& b) {
#pragma unroll
    for (int m = 32; m > 0; m >>= 1) {
        a += __shfl_xor(a, m, 64);
        b += __shfl_xor(b, m, 64);
    }
}

__global__ __launch_bounds__(512, 2)
void qtb_fused8(const float* __restrict__ x,
                const float* __restrict__ th_a,
                const float* __restrict__ Wc,
                const float* __restrict__ bc,
                const float* __restrict__ g1,
                const float* __restrict__ be1,
                const float* __restrict__ th_f,
                const float* __restrict__ W1,
                const float* __restrict__ b1,
                const float* __restrict__ W2,
                const float* __restrict__ b2,
                const float* __restrict__ g2,
                const float* __restrict__ be2,
                float* __restrict__ out)
{
    __shared__ __align__(16) int2      sWc[16 * 64];     //  8 KB
    __shared__ __align__(16) int4      sW1[256];         //  4 KB
    __shared__ __align__(16) _Float16  sW2t[64][264];    // 33 KB (pad 8)
    __shared__ __align__(16) _Float16  sH[16][264];      //  8.3 KB (pad 8)
    __shared__ __align__(16) float     sO[16][66];       //  4.1 KB (pad 2)

    const int tid  = threadIdx.x;                 // 0..511
    const int lane = tid & 63;
    const int wv   = tid >> 6;                    // 0..7
    const int w    = lane & 7;
    const int gb   = lane & ~7;
    const int tok0 = (blockIdx.x * 8 + wv) * 2;   // 2 tokens per wave

    // ---- stage weights into LDS (float4 global loads) ----
    // W2 transposed to f16 [e][k]: all 512 threads, one (e-quad, k-octet) each
    {
        int k0 = (tid & 31) * 8;         // 0..248
        int e0 = (tid >> 5) * 4;         // 0..60
        float4 r[8];
#pragma unroll
        for (int i = 0; i < 8; ++i)
            r[i] = *(const float4*)&W2[(k0 + i) * 64 + e0];
        const float* f = (const float*)r;   // f[i*4 + j] = W2[k0+i][e0+j]
#pragma unroll
        for (int j = 0; j < 4; ++j) {
            int4 wj = make_int4(pk(f[0 * 4 + j], f[1 * 4 + j]),
                                pk(f[2 * 4 + j], f[3 * 4 + j]),
                                pk(f[4 * 4 + j], f[5 * 4 + j]),
                                pk(f[6 * 4 + j], f[7 * 4 + j]));
            *(int4*)&sW2t[e0 + j][k0] = wj;
        }
    }
    // Wc: threads 0..255 (16 q2 x 16 e-groups)
    if (tid < 256) {
        int q2 = tid >> 4;               // 0..15
        int e0 = (tid & 15) * 4;
        const float* b = Wc + e0;
        float4 r0 = *(const float4*)&b[(2 * q2     ) * 64];
        float4 r1 = *(const float4*)&b[(2 * q2 +  1) * 64];
        float4 r2 = *(const float4*)&b[(2 * q2 + 32) * 64];
        float4 r3 = *(const float4*)&b[(2 * q2 + 33) * 64];
        int4* dst = (int4*)&sWc[q2 * 64 + e0];
        dst[0] = make_int4(pk(r0.x, r2.x), pk(r1.x, r3.x),
                           pk(r0.y, r2.y), pk(r1.y, r3.y));
        dst[1] = make_int4(pk(r0.z, r2.z), pk(r1.z, r3.z),
                           pk(r0.w, r2.w), pk(r1.w, r3.w));
    } else if (tid < 320) {
        // W1: threads 256..319 (64 j-groups)
        int j0 = (tid - 256) * 4;
        float4 r[8];
#pragma unroll
        for (int k = 0; k < 8; ++k) r[k] = *(const float4*)&W1[k * 256 + j0];
        const float* f = (const float*)r;   // f[k*4 + j]
        int4* dst = &sW1[j0];
#pragma unroll
        for (int j = 0; j < 4; ++j)
            dst[j] = make_int4(pk(f[0 * 4 + j], f[4 * 4 + j]),
                               pk(f[1 * 4 + j], f[5 * 4 + j]),
                               pk(f[2 * 4 + j], f[6 * 4 + j]),
                               pk(f[3 * 4 + j], f[7 * 4 + j]));
    }

    // independent global loads issued while staging is in flight
    float xr[2];
#pragma unroll
    for (int t = 0; t < 2; ++t) xr[t] = x[(tok0 + t) * 64 + lane];

    const float C0a = __cosf(th_a[0]);
    const float T1a = th_a[1];
    const float C3a = __cosf(th_a[3]);
    const float T4a = th_a[4];
    const float C0f = __cosf(th_f[0]);
    const float T1f = th_f[1];
    const float C3f = __cosf(th_f[3]);
    const float T4f = th_f[4];

    const float bcL = bc[lane], g1L = g1[lane], be1L = be1[lane];
    const float b2L = b2[lane], g2L = g2[lane], be2L = be2[lane];
    float b1L[4];
#pragma unroll
    for (int r = 0; r < 4; ++r) b1L[r] = b1[r * 64 + lane];

    // ---- quantum attention expectations (closed form, in registers) ----
    const float dA = (w == 2) ? T4a : ((w == 3) ? T1a : 0.0f);
    int zp[2];
#pragma unroll
    for (int t = 0; t < 2; ++t) {
        float c  = __cosf(xr[t] + dA);
        float c0 = __shfl(c, gb, 64);       // cos(a0) of this 8-group
        float c1 = __shfl(c, gb + 1, 64);   // cos(a1)
        float zz = c * ((w == 0) ? C0a : ((w == 6) ? C3a : 1.0f));
        if (w == 4) zz = c * c1;
        if (w == 7) zz = C0a * c0 * c;
        // readlane at q < 32 yields (z[q], z[q+32])
        zp[t] = pk(zz, __shfl_xor(zz, 32, 64));
    }

    __syncthreads();   // staging complete

    // ---- attn = Z @ Wc + bc : K=64 as 32 fp16-pair words, int2 reads ----
    float acc[2] = {bcL, bcL};
#pragma unroll 4
    for (int q2 = 0; q2 < 16; ++q2) {
        int2 wq = sWc[q2 * 64 + lane];
        int q = 2 * q2;
        acc[0] = fdot2i(rl_i(zp[0], q),     wq.x, acc[0]);
        acc[1] = fdot2i(rl_i(zp[1], q),     wq.x, acc[1]);
        acc[0] = fdot2i(rl_i(zp[0], q + 1), wq.y, acc[0]);
        acc[1] = fdot2i(rl_i(zp[1], q + 1), wq.y, acc[1]);
    }

    // ---- y = LN(x + attn) ----
    float y[2];
#pragma unroll
    for (int t = 0; t < 2; ++t) {
        float v = xr[t] + acc[t];
        float s = v, s2 = v * v;
        wave_sum2(s, s2);
        float m   = s * 0.015625f;
        float var = s2 * 0.015625f - m * m;
        y[t] = (v - m) * rsqrtf(var + 1e-5f) * g1L + be1L;
    }

    // ---- ffn quantum gate (y[:, :8]) + h = relu(QF @ W1 + b1) -> sH ----
    int4 w1q[4];
#pragma unroll
    for (int r = 0; r < 4; ++r) w1q[r] = sW1[r * 64 + lane];

    const float dF = (w == 2) ? T4f : ((w == 3) ? T1f : 0.0f);
#pragma unroll
    for (int t = 0; t < 2; ++t) {
        float cy = __cosf(y[t] + dF);        // meaningful on lanes 0..7
        float c0 = rl_f(cy, 0);
        float c1 = rl_f(cy, 1);
        float qz = cy * ((w == 0) ? C0f : ((w == 6) ? C3f : 1.0f));
        if (w == 4) qz = cy * c1;
        if (w == 7) qz = C0f * c0 * cy;
        int qp0 = pk(rl_f(qz, 0), rl_f(qz, 4));   // pairs (k, k+4)
        int qp1 = pk(rl_f(qz, 1), rl_f(qz, 5));
        int qp2 = pk(rl_f(qz, 2), rl_f(qz, 6));
        int qp3 = pk(rl_f(qz, 3), rl_f(qz, 7));
#pragma unroll
        for (int r = 0; r < 4; ++r) {
            float a = b1L[r];
            a = fdot2i(qp0, w1q[r].x, a);
            a = fdot2i(qp1, w1q[r].y, a);
            a = fdot2i(qp2, w1q[r].z, a);
            a = fdot2i(qp3, w1q[r].w, a);
            sH[wv * 2 + t][r * 64 + lane] = (_Float16)fmaxf(a, 0.0f);
        }
    }

    __syncthreads();   // sH complete (sW2t done since barrier 1)

    // ---- ffn2 = H @ W2 : one 16x64x256 GEMM, waves 0..3, 8 MFMA each ----
    if (wv < 4) {
        const int col = lane & 15;       // token row (A) / e col (B,D)
        const int kg  = lane >> 4;       // 0..3
        f32x4 cacc = {0.0f, 0.0f, 0.0f, 0.0f};
#pragma unroll
        for (int ks = 0; ks < 8; ++ks) {
            f16x8 af = *(const f16x8*)&sH[col][ks * 32 + kg * 8];
            f16x8 bf = *(const f16x8*)&sW2t[wv * 16 + col][ks * 32 + kg * 8];
            cacc = __builtin_amdgcn_mfma_f32_16x16x32_f16(af, bf, cacc, 0, 0, 0);
        }
#pragma unroll
        for (int r = 0; r < 4; ++r)
            sO[kg * 4 + r][wv * 16 + col] = cacc[r];
    }

    __syncthreads();   // sO complete

    // ---- out = LN(y + ffn2 + b2) ----
#pragma unroll
    for (int t = 0; t < 2; ++t) {
        float v = y[t] + b2L + sO[wv * 2 + t][lane];
        float s = v, s2 = v * v;
        wave_sum2(s, s2);
        float m   = s * 0.015625f;
        float var = s2 * 0.015625f - m * m;
        out[(tok0 + t) * 64 + lane] = (v - m) * rsqrtf(var + 1e-5f) * g2L + be2L;
    }
}

extern "C" void kernel_launch(void* const* d_in, const int* in_sizes, int n_in,
                              void* d_out, int out_size, void* d_ws, size_t ws_size,
                              hipStream_t stream)
{
    const float* x   = (const float*)d_in[0];
    const float* at  = (const float*)d_in[1];
    const float* Wc  = (const float*)d_in[2];
    const float* bcp = (const float*)d_in[3];
    const float* g1  = (const float*)d_in[4];
    const float* be1 = (const float*)d_in[5];
    const float* ft  = (const float*)d_in[6];
    const float* W1  = (const float*)d_in[7];
    const float* b1  = (const float*)d_in[8];
    const float* W2  = (const float*)d_in[9];
    const float* b2  = (const float*)d_in[10];
    const float* g2  = (const float*)d_in[11];
    const float* be2 = (const float*)d_in[12];
    float* out = (float*)d_out;

    // 4096 tokens = 256 blocks x 8 waves x 2 tokens; single dispatch,
    // 1 block/CU, ~58 KB LDS, 3 barriers, ffn2 on the matrix pipe.
    qtb_fused8<<<256, 512, 0, stream>>>(x, at, Wc, bcp, g1, be1, ft,
                                        W1, b1, W2, b2, g2, be2, out);
}

// Round 9
// 11.397 us; speedup vs baseline: 1.6110x; 1.0156x over previous
//
#include <hip/hip_runtime.h>

// Fused quantum-transformer block, v9: BOTH GEMMs on the matrix pipe.
// 256 blocks x 512 threads (1 block/CU, 8 waves, 2 waves/SIMD), 2 tokens/wave.
// attn = Z@Wc via mfma (waves 0-3), ffn2 = H@W2 via mfma (waves 4-7);
// ffn1 stays readlane+fdot2 (K=8, too small for MFMA).
//
// Closed-form circuit (verified round 1): OPS = ry(0,t0) rx(3,t1) rz(5,t2)
// cx(1,4) ry(6,t3) rx(2,t4) cx(0,7) rz(4,t5) on RX(a_w)-encoded product state.
//   z0 = cos(t0) cos(a0)          z4 = cos(a1) cos(a4)
//   z1 = cos(a1)                  z5 = cos(a5)
//   z2 = cos(a2 + t4)             z6 = cos(t3) cos(a6)
//   z3 = cos(a3 + t1)             z7 = cos(t0) cos(a0) cos(a7)
//
// LDS:
//   sWct[e][q] f16, pad 72 : Wc transposed                       9.2 KB
//   sW1 [j]    int4        : (pk(W1[k][j],W1[k+4][j]) k=0..3)    4 KB
//   sW2t[e][k] f16, pad 264: W2 transposed                      33 KB
//   sZ  [tok][q] f16 pad 72: attention-circuit expectations      2.3 KB
//   sA  [tok][e] f32 pad 66: attn GEMM output                    4.2 KB
//   sH  [tok][c] f16 pad264: ffn1 activations                    8.3 KB
//   sO  [tok][e] f32 pad 66: ffn2 GEMM output                    4.2 KB

typedef _Float16 h2f   __attribute__((ext_vector_type(2)));
typedef _Float16 f16x8 __attribute__((ext_vector_type(8)));
typedef float    f32x4 __attribute__((ext_vector_type(4)));

__device__ __forceinline__ int pk(float a, float b) {
    return __builtin_bit_cast(int, __builtin_amdgcn_cvt_pkrtz(a, b));
}
__device__ __forceinline__ float fdot2i(int a, int b, float c) {
    return __builtin_amdgcn_fdot2(__builtin_bit_cast(h2f, a),
                                  __builtin_bit_cast(h2f, b), c, false);
}
__device__ __forceinline__ float rl_f(float v, int l) {
    return __int_as_float(__builtin_amdgcn_readlane(__float_as_int(v), l));
}
__device__ __forceinline__ void wave_sum2(float& a, float& b) {
#pragma unroll
    for (int m = 32; m > 0; m >>= 1) {
        a += __shfl_xor(a, m, 64);
        b += __shfl_xor(b, m, 64);
    }
}

__global__ __launch_bounds__(512, 2)
void qtb_fused9(const float* __restrict__ x,
                const float* __restrict__ th_a,
                const float* __restrict__ Wc,
                const float* __restrict__ bc,
                const float* __restrict__ g1,
                const float* __restrict__ be1,
                const float* __restrict__ th_f,
                const float* __restrict__ W1,
                const float* __restrict__ b1,
                const float* __restrict__ W2,
                const float* __restrict__ b2,
                const float* __restrict__ g2,
                const float* __restrict__ be2,
                float* __restrict__ out)
{
    __shared__ __align__(16) _Float16  sWct[64][72];     //  9.2 KB
    __shared__ __align__(16) int4      sW1[256];         //  4 KB
    __shared__ __align__(16) _Float16  sW2t[64][264];    // 33 KB
    __shared__ __align__(16) _Float16  sZ[16][72];       //  2.3 KB
    __shared__ __align__(16) float     sA[16][66];       //  4.2 KB
    __shared__ __align__(16) _Float16  sH[16][264];      //  8.3 KB
    __shared__ __align__(16) float     sO[16][66];       //  4.2 KB

    const int tid  = threadIdx.x;                 // 0..511
    const int lane = tid & 63;
    const int wv   = tid >> 6;                    // 0..7
    const int w    = lane & 7;
    const int gb   = lane & ~7;
    const int tok0 = (blockIdx.x * 8 + wv) * 2;   // 2 tokens per wave
    const int tl   = wv * 2;                      // local token base

    // ---- stage weights into LDS (float4 global loads) ----
    // W2 transposed to f16 [e][k]: all 512 threads
    {
        int k0 = (tid & 31) * 8;         // 0..248
        int e0 = (tid >> 5) * 4;         // 0..60
        float4 r[8];
#pragma unroll
        for (int i = 0; i < 8; ++i)
            r[i] = *(const float4*)&W2[(k0 + i) * 64 + e0];
        const float* f = (const float*)r;   // f[i*4 + j] = W2[k0+i][e0+j]
#pragma unroll
        for (int j = 0; j < 4; ++j)
            *(int4*)&sW2t[e0 + j][k0] =
                make_int4(pk(f[0 * 4 + j], f[1 * 4 + j]),
                          pk(f[2 * 4 + j], f[3 * 4 + j]),
                          pk(f[4 * 4 + j], f[5 * 4 + j]),
                          pk(f[6 * 4 + j], f[7 * 4 + j]));
    }
    // Wc transposed to f16 [e][q]: threads 0..127
    if (tid < 128) {
        int q0 = (tid & 7) * 8;          // 0..56
        int e0 = (tid >> 3) * 4;         // 0..60
        float4 r[8];
#pragma unroll
        for (int i = 0; i < 8; ++i)
            r[i] = *(const float4*)&Wc[(q0 + i) * 64 + e0];
        const float* f = (const float*)r;   // f[i*4 + j] = Wc[q0+i][e0+j]
#pragma unroll
        for (int j = 0; j < 4; ++j)
            *(int4*)&sWct[e0 + j][q0] =
                make_int4(pk(f[0 * 4 + j], f[1 * 4 + j]),
                          pk(f[2 * 4 + j], f[3 * 4 + j]),
                          pk(f[4 * 4 + j], f[5 * 4 + j]),
                          pk(f[6 * 4 + j], f[7 * 4 + j]));
    } else if (tid < 192) {
        // W1: threads 128..191, packed pairs (k, k+4)
        int j0 = (tid - 128) * 4;
        float4 r[8];
#pragma unroll
        for (int k = 0; k < 8; ++k) r[k] = *(const float4*)&W1[k * 256 + j0];
        const float* f = (const float*)r;   // f[k*4 + j]
#pragma unroll
        for (int j = 0; j < 4; ++j)
            sW1[j0 + j] = make_int4(pk(f[0 * 4 + j], f[4 * 4 + j]),
                                    pk(f[1 * 4 + j], f[5 * 4 + j]),
                                    pk(f[2 * 4 + j], f[6 * 4 + j]),
                                    pk(f[3 * 4 + j], f[7 * 4 + j]));
    }

    // independent global loads issued while staging is in flight
    float xr[2];
#pragma unroll
    for (int t = 0; t < 2; ++t) xr[t] = x[(tok0 + t) * 64 + lane];

    const float C0a = __cosf(th_a[0]);
    const float T1a = th_a[1];
    const float C3a = __cosf(th_a[3]);
    const float T4a = th_a[4];
    const float C0f = __cosf(th_f[0]);
    const float T1f = th_f[1];
    const float C3f = __cosf(th_f[3]);
    const float T4f = th_f[4];

    const float bcL = bc[lane], g1L = g1[lane], be1L = be1[lane];
    const float b2L = b2[lane], g2L = g2[lane], be2L = be2[lane];
    float b1L[4];
#pragma unroll
    for (int r = 0; r < 4; ++r) b1L[r] = b1[r * 64 + lane];

    // ---- quantum attention expectations -> sZ (f16) ----
    const float dA = (w == 2) ? T4a : ((w == 3) ? T1a : 0.0f);
#pragma unroll
    for (int t = 0; t < 2; ++t) {
        float c  = __cosf(xr[t] + dA);
        float c0 = __shfl(c, gb, 64);       // cos(a0) of this 8-group
        float c1 = __shfl(c, gb + 1, 64);   // cos(a1)
        float zz = c * ((w == 0) ? C0a : ((w == 6) ? C3a : 1.0f));
        if (w == 4) zz = c * c1;
        if (w == 7) zz = C0a * c0 * c;
        sZ[tl + t][lane] = (_Float16)zz;
    }

    __syncthreads();   // barrier 1: staging + sZ complete

    const int col = lane & 15;
    const int kg  = lane >> 4;

    // ffn2 B-fragment prefetch on waves 4..7 (idle until barrier 3)
    f16x8 bf2[8];
    if (wv >= 4) {
#pragma unroll
        for (int ks = 0; ks < 8; ++ks)
            bf2[ks] = *(const f16x8*)&sW2t[(wv - 4) * 16 + col][ks * 32 + kg * 8];
    }

    // ---- attn GEMM: A=sZ[16][64], B=sWct tile, waves 0..3, 2 MFMA ----
    if (wv < 4) {
        f32x4 cacc = {0.0f, 0.0f, 0.0f, 0.0f};
#pragma unroll
        for (int ks = 0; ks < 2; ++ks) {
            f16x8 af = *(const f16x8*)&sZ[col][ks * 32 + kg * 8];
            f16x8 bf = *(const f16x8*)&sWct[wv * 16 + col][ks * 32 + kg * 8];
            cacc = __builtin_amdgcn_mfma_f32_16x16x32_f16(af, bf, cacc, 0, 0, 0);
        }
#pragma unroll
        for (int r = 0; r < 4; ++r)
            sA[kg * 4 + r][wv * 16 + col] = cacc[r];
    }

    __syncthreads();   // barrier 2: sA complete

    // ---- y = LN(x + attn + bc) ----
    float y[2];
#pragma unroll
    for (int t = 0; t < 2; ++t) {
        float v = xr[t] + sA[tl + t][lane] + bcL;
        float s = v, s2 = v * v;
        wave_sum2(s, s2);
        float m   = s * 0.015625f;
        float var = s2 * 0.015625f - m * m;
        y[t] = (v - m) * rsqrtf(var + 1e-5f) * g1L + be1L;
    }

    // ---- ffn quantum gate (y[:, :8]) + h = relu(QF @ W1 + b1) -> sH ----
    int4 w1q[4];
#pragma unroll
    for (int r = 0; r < 4; ++r) w1q[r] = sW1[r * 64 + lane];

    const float dF = (w == 2) ? T4f : ((w == 3) ? T1f : 0.0f);
#pragma unroll
    for (int t = 0; t < 2; ++t) {
        float cy = __cosf(y[t] + dF);        // meaningful on lanes 0..7
        float c0 = rl_f(cy, 0);
        float c1 = rl_f(cy, 1);
        float qz = cy * ((w == 0) ? C0f : ((w == 6) ? C3f : 1.0f));
        if (w == 4) qz = cy * c1;
        if (w == 7) qz = C0f * c0 * cy;
        int qp0 = pk(rl_f(qz, 0), rl_f(qz, 4));   // pairs (k, k+4)
        int qp1 = pk(rl_f(qz, 1), rl_f(qz, 5));
        int qp2 = pk(rl_f(qz, 2), rl_f(qz, 6));
        int qp3 = pk(rl_f(qz, 3), rl_f(qz, 7));
#pragma unroll
        for (int r = 0; r < 4; ++r) {
            float a = b1L[r];
            a = fdot2i(qp0, w1q[r].x, a);
            a = fdot2i(qp1, w1q[r].y, a);
            a = fdot2i(qp2, w1q[r].z, a);
            a = fdot2i(qp3, w1q[r].w, a);
            sH[tl + t][r * 64 + lane] = (_Float16)fmaxf(a, 0.0f);
        }
    }

    __syncthreads();   // barrier 3: sH complete

    // ---- ffn2 GEMM: 16x64x256, waves 4..7, 8 MFMA each ----
    if (wv >= 4) {
        f32x4 cacc = {0.0f, 0.0f, 0.0f, 0.0f};
#pragma unroll
        for (int ks = 0; ks < 8; ++ks) {
            f16x8 af = *(const f16x8*)&sH[col][ks * 32 + kg * 8];
            cacc = __builtin_amdgcn_mfma_f32_16x16x32_f16(af, bf2[ks], cacc, 0, 0, 0);
        }
#pragma unroll
        for (int r = 0; r < 4; ++r)
            sO[kg * 4 + r][(wv - 4) * 16 + col] = cacc[r];
    }

    __syncthreads();   // barrier 4: sO complete

    // ---- out = LN(y + ffn2 + b2) ----
#pragma unroll
    for (int t = 0; t < 2; ++t) {
        float v = y[t] + b2L + sO[tl + t][lane];
        float s = v, s2 = v * v;
        wave_sum2(s, s2);
        float m   = s * 0.015625f;
        float var = s2 * 0.015625f - m * m;
        out[(tok0 + t) * 64 + lane] = (v - m) * rsqrtf(var + 1e-5f) * g2L + be2L;
    }
}

extern "C" void kernel_launch(void* const* d_in, const int* in_sizes, int n_in,
                              void* d_out, int out_size, void* d_ws, size_t ws_size,
                              hipStream_t stream)
{
    const float* x   = (const float*)d_in[0];
    const float* at  = (const float*)d_in[1];
    const float* Wc  = (const float*)d_in[2];
    const float* bcp = (const float*)d_in[3];
    const float* g1  = (const float*)d_in[4];
    const float* be1 = (const float*)d_in[5];
    const float* ft  = (const float*)d_in[6];
    const float* W1  = (const float*)d_in[7];
    const float* b1  = (const float*)d_in[8];
    const float* W2  = (const float*)d_in[9];
    const float* b2  = (const float*)d_in[10];
    const float* g2  = (const float*)d_in[11];
    const float* be2 = (const float*)d_in[12];
    float* out = (float*)d_out;

    // 4096 tokens = 256 blocks x 8 waves x 2 tokens; single dispatch,
    // 1 block/CU, ~65 KB LDS, 4 barriers, both GEMMs on the matrix pipe.
    qtb_fused9<<<256, 512, 0, stream>>>(x, at, Wc, bcp, g1, be1, ft,
                                        W1, b1, W2, b2, g2, be2, out);
}